// Round 6
// baseline (417.542 us; speedup 1.0000x reference)
//
#include <hip/hip_runtime.h>

// Fused SLAYER 2-layer SNN forward, time-chunked bitmask version.
// R6 = R5 grid (16x8 tiles, 1024 blocks -> 4 blocks/CU) + R3 launch bounds.
// Lesson from R4/R5: on this hipcc, __launch_bounds__ second arg == 4 caps
// VGPR at 64 -> heavy scratch spills (WRITE_SIZE +75GB, VALUBusy collapse).
// Plain __launch_bounds__(256) compiles these loops at 116 VGPR (R3), and
// floor(512/116) = 4 waves/SIMD already allows the 4 blocks/CU we need.
//
// psp commutes with the per-timestep spatial conv -> conv BINARY spikes,
// apply psp after. Spikes live as bitmasks; convs amortize LDS mask/weight
// reads over TC=10 timesteps. Recurrence arithmetic identical to R3 (absmax 0).

#define TW   16                 // tile width
#define TH   8                  // tile height
#define R1S  (TW + 6)           // 22: x-mask region row stride/width
#define R1R  (TH + 6)           // 14: x-mask region rows
#define R1N  (R1S * R1R)        // 308
#define R2S  (TW + 2)           // 18: layer-1 spike region width
#define R2R  (TH + 2)           // 10: rows
#define R2N  (R2S * R2R)        // 180
#define TC   10                 // timesteps per chunk (50 = 5 chunks)

__global__ __launch_bounds__(256)
void snn_fused(const float* __restrict__ xin,
               const float* __restrict__ w1,
               const float* __restrict__ w2,
               float* __restrict__ out)
{
    __shared__ __align__(16) uint2    xm[4][R1N];   // input spike masks (all 50 t)
    __shared__ unsigned               s1m[4][R2N];  // layer-1 spike masks (per chunk)
    __shared__ __align__(16) float    wL1[400];     // [ic][dy][dx][oc]
    __shared__ __align__(16) float    wL2[144];     // [ic][dy][dx][oc]

    const int tid = threadIdx.x;
    const int n   = blockIdx.z;
    const int Y0  = blockIdx.y * TH;
    const int X0  = blockIdx.x * TW;

    // ---- stage weights, transposed to [ic][dy][dx][oc] ----
    for (int i = tid; i < 400; i += 256) {
        int oc = i & 3, r = i >> 2;
        int ic = r / 25, r2 = r - ic * 25;
        int dy = r2 / 5, dx = r2 - dy * 5;
        wL1[i] = w1[((oc * 4 + ic) * 5 + dy) * 5 + dx];
    }
    if (tid < 144) {
        int oc = tid & 3, r = tid >> 2;
        int ic = r / 9, r2 = r - ic * 9;
        int dy = r2 / 3, dx = r2 - dy * 3;
        wL2[tid] = w2[((oc * 4 + ic) * 3 + dy) * 3 + dx];
    }

    // ---- pack input spikes (50 floats) into 64-bit masks, once ----
#pragma unroll
    for (int s = 0; s < 2; ++s) {
        int hp = tid + s * 256;
        if (hp < R1N) {
            int hy = hp / R1S, hx = hp - hy * R1S;
            int gy = Y0 + hy - 3, gx = X0 + hx - 3;
            bool inimg = gy >= 0 && gy < 128 && gx >= 0 && gx < 128;
#pragma unroll
            for (int c = 0; c < 4; ++c) {
                unsigned m0 = 0, m1 = 0;
                if (inimg) {
                    const float2* p = (const float2*)
                        (xin + ((size_t)(((n * 4 + c) * 128 + gy) * 128 + gx)) * 50);
#pragma unroll
                    for (int j = 0; j < 25; ++j) {
                        float2 v = p[j];
                        unsigned b0 = (v.x != 0.f) ? 1u : 0u;
                        unsigned b1 = (v.y != 0.f) ? 1u : 0u;
                        int k = 2 * j;
                        if (k < 32) m0 |= (b0 << k) | (b1 << (k + 1));
                        else        m1 |= (b0 << (k - 32)) | (b1 << (k - 31));
                    }
                }
                xm[c][hp] = make_uint2(m0, m1);
            }
        }
    }

    // ---- layer-1 region slot (10x18 = 180 px, single slot) ----
    const bool cw = (tid < R2N);
    const int cy = tid / R2S;
    const int cx = tid - cy * R2S;
    const bool cin = cw && (Y0 + cy - 1) >= 0 && (Y0 + cy - 1) < 128
                        && (X0 + cx - 1) >= 0 && (X0 + cx - 1) < 128;
    const int xbase = cy * R1S + cx;

    // ---- interior pixel (8x16 = 128 px, waves 0-1) ----
    const bool iw = (tid < TW * TH);
    const int iy = tid >> 4, ix = tid & 15;
    const int ibase = iy * R2S + ix;

    // persistent recurrence states
    float s1a[4] = {}, s2a[4] = {}, s1b[4] = {}, s2b[4] = {};
    float s1c[4] = {}, s2c[4] = {}, s1d[4] = {}, s2d[4] = {};
    unsigned long long om[4] = {};

    const float R1  = 0.36787944117144233f;   // exp(-1/1)
    const float CO1 = 2.7182818284590452f;    // e/1
    const float R2  = 0.60653065971263342f;   // exp(-1/2)
    const float CO2 = 1.3591409142295226f;    // e/2
    const float CRF = -54.365636569180902f;   // -20e == -40e/2

    __syncthreads();

    for (int chk = 0; chk < 5; ++chk) {
        const int t0 = chk * TC;

        // ================= layer 1: conv1 + psp1 + spike1 =================
        if (cw) {
            float a[TC][4];
#pragma unroll
            for (int u = 0; u < TC; ++u) { a[u][0]=0.f; a[u][1]=0.f; a[u][2]=0.f; a[u][3]=0.f; }
            if (cin) {
#pragma unroll 1
                for (int ic = 0; ic < 4; ++ic) {
                    const uint2*  xp = &xm[ic][xbase];
                    const float4* wp = (const float4*)&wL1[ic * 100];
#pragma unroll 1
                    for (int dy = 0; dy < 5; ++dy) {
#pragma unroll
                        for (int dx = 0; dx < 5; ++dx) {
                            uint2 m = xp[dx];
                            unsigned long long mm =
                                ((unsigned long long)m.y << 32) | m.x;
                            unsigned win = (unsigned)(mm >> t0);
                            float4 w = wp[dx];
#pragma unroll
                            for (int u = 0; u < TC; ++u) {
                                float f = (float)((win >> u) & 1u);
                                a[u][0] = fmaf(f, w.x, a[u][0]);
                                a[u][1] = fmaf(f, w.y, a[u][1]);
                                a[u][2] = fmaf(f, w.z, a[u][2]);
                                a[u][3] = fmaf(f, w.w, a[u][3]);
                            }
                        }
                        xp += R1S; wp += 5;
                    }
                }
            }
            unsigned cm[4] = {0, 0, 0, 0};
#pragma unroll
            for (int u = 0; u < TC; ++u) {
#pragma unroll
                for (int oc = 0; oc < 4; ++oc) {
                    float ao  = CO1 * s2a[oc];
                    float ns1 = fmaf(R1, s1a[oc], a[u][oc]);
                    s1a[oc] = ns1;
                    s2a[oc] = fmaf(R1, s2a[oc], R1 * ns1);
                    float mv = fmaf(CRF, s2b[oc], ao);
                    unsigned b = (mv >= 20.f) ? 1u : 0u;
                    float spf = (float)b;
                    float nb1 = fmaf(R1, s1b[oc], spf);
                    s1b[oc] = nb1;
                    s2b[oc] = fmaf(R1, s2b[oc], R1 * nb1);
                    cm[oc] |= b << u;
                }
            }
            s1m[0][tid] = cm[0];
            s1m[1][tid] = cm[1];
            s1m[2][tid] = cm[2];
            s1m[3][tid] = cm[3];
        }
        __syncthreads();

        // ================= layer 2: conv2 + psp2 + spike2 =================
        if (iw) {
            float a[TC][4];
#pragma unroll
            for (int u = 0; u < TC; ++u) { a[u][0]=0.f; a[u][1]=0.f; a[u][2]=0.f; a[u][3]=0.f; }
#pragma unroll 1
            for (int ic = 0; ic < 4; ++ic) {
                const unsigned* sp = &s1m[ic][ibase];
                const float4*   wp = (const float4*)&wL2[ic * 36];
#pragma unroll 1
                for (int dy = 0; dy < 3; ++dy) {
#pragma unroll
                    for (int dx = 0; dx < 3; ++dx) {
                        unsigned win = sp[dx];
                        float4 w = wp[dx];
#pragma unroll
                        for (int u = 0; u < TC; ++u) {
                            float f = (float)((win >> u) & 1u);
                            a[u][0] = fmaf(f, w.x, a[u][0]);
                            a[u][1] = fmaf(f, w.y, a[u][1]);
                            a[u][2] = fmaf(f, w.z, a[u][2]);
                            a[u][3] = fmaf(f, w.w, a[u][3]);
                        }
                    }
                    sp += R2S; wp += 3;
                }
            }
            unsigned cm[4] = {0, 0, 0, 0};
#pragma unroll
            for (int u = 0; u < TC; ++u) {
#pragma unroll
                for (int oc = 0; oc < 4; ++oc) {
                    float ao  = CO2 * s2c[oc];
                    float ns1 = fmaf(R2, s1c[oc], a[u][oc]);
                    s1c[oc] = ns1;
                    s2c[oc] = fmaf(R2, s2c[oc], R2 * ns1);
                    float mv = fmaf(CRF, s2d[oc], ao);
                    unsigned b = (mv >= 40.f) ? 1u : 0u;
                    float spf = (float)b;
                    float nd1 = fmaf(R2, s1d[oc], spf);
                    s1d[oc] = nd1;
                    s2d[oc] = fmaf(R2, s2d[oc], R2 * nd1);
                    cm[oc] |= b << u;
                }
            }
#pragma unroll
            for (int oc = 0; oc < 4; ++oc)
                om[oc] |= (unsigned long long)cm[oc] << t0;
        }
        __syncthreads();   // protect s1m reads vs next chunk's writes
    }

    // ---- epilogue: expand output bitmasks to floats ----
    if (iw) {
#pragma unroll
        for (int c = 0; c < 4; ++c) {
            float* p = out + ((size_t)(((n * 4 + c) * 128 + (Y0 + iy)) * 128 + (X0 + ix))) * 50;
            unsigned long long m = om[c];
#pragma unroll
            for (int j = 0; j < 25; ++j) {
                int k = 2 * j;
                float2 v;
                v.x = (float)((unsigned)(m >> k) & 1u);
                v.y = (float)((unsigned)(m >> (k + 1)) & 1u);
                *(float2*)(p + k) = v;
            }
        }
    }
}

extern "C" void kernel_launch(void* const* d_in, const int* in_sizes, int n_in,
                              void* d_out, int out_size, void* d_ws, size_t ws_size,
                              hipStream_t stream) {
    (void)in_sizes; (void)n_in; (void)out_size; (void)d_ws; (void)ws_size;
    const float* x  = (const float*)d_in[0];
    const float* w1 = (const float*)d_in[1];
    const float* w2 = (const float*)d_in[2];
    float* o = (float*)d_out;
    dim3 grid(128 / TW, 128 / TH, 8);   // 8 x 16 x 8 = 1024 blocks
    dim3 block(256);
    hipLaunchKernelGGL(snn_fused, grid, block, 0, stream, x, w1, w2, o);
}

// Round 7
// 312.015 us; speedup vs baseline: 1.3382x; 1.3382x over previous
//
#include <hip/hip_runtime.h>

// Fused SLAYER 2-layer SNN forward — 3-kernel balanced bitmask pipeline.
// R7: R6's single fused kernel was wave-imbalanced (L1 conv on waves 0-2,
// L2 on waves 0-1, wave i -> SIMD i%4 => SIMD0 saturated, SIMD3 idle;
// VALUBusy 50%, dur pinned at ~300us regardless of occupancy). Split into
// 3 dispatches where EVERY lane does identical work:
//   A: pack input spikes -> uint2 masks (memory-bound)
//   B: layer1 conv5x5+psp+spike, 1 thread = 1 pixel, masks via LDS halo
//   C: layer2 conv3x3+psp+spike + coalesced output expansion
// Masks flow through d_ws (2 x 4MB, L2/L3-resident). psp commutes with the
// per-timestep spatial conv -> conv binary spikes, psp after. Recurrence
// arithmetic identical to the passing R3/R6 kernels (absmax 0).

#define TC 10   // timesteps per chunk (50 = 5 chunks)

// ---------------- kernel A: pack spikes to bitmasks ----------------
__global__ __launch_bounds__(256)
void snn_pack(const float* __restrict__ xin, uint2* __restrict__ xmg)
{
    const int i = blockIdx.x * 256 + threadIdx.x;    // flat (n,c,y,x), 524288
    const float2* p = (const float2*)(xin + (size_t)i * 50);
    unsigned m0 = 0, m1 = 0;
#pragma unroll
    for (int j = 0; j < 25; ++j) {
        float2 v = p[j];
        unsigned b0 = (v.x != 0.f) ? 1u : 0u;
        unsigned b1 = (v.y != 0.f) ? 1u : 0u;
        int k = 2 * j;
        if (k < 32) m0 |= (b0 << k) | (b1 << (k + 1));
        else        m1 |= (b0 << (k - 32)) | (b1 << (k - 31));
    }
    const int n  = i >> 16;          // 4*128*128 = 65536 per batch
    const int c  = (i >> 14) & 3;
    const int yx = i & 16383;
    xmg[((size_t)((n << 14) + yx)) * 4 + c] = make_uint2(m0, m1);
}

// ---------------- kernel B: layer 1 ----------------
#define HS1 20            // halo region 20x20 for 16x16 tile, 5x5 conv
#define HP1 21            // padded LDS plane stride
__global__ __launch_bounds__(256)
void snn_l1(const uint2* __restrict__ xmg, const float* __restrict__ w1,
            uint2* __restrict__ s1g)
{
    __shared__ __align__(16) uint2 xs[4][HS1 * HP1];
    __shared__ __align__(16) float wL1[400];        // [ic][dy][dx][oc]

    const int tid = threadIdx.x;
    const int n = blockIdx.z, Y0 = blockIdx.y * 16, X0 = blockIdx.x * 16;

    if (tid < 400) {
        int oc = tid & 3, r = tid >> 2;
        int ic = r / 25, r2 = r - ic * 25;
        int dy = r2 / 5, dx = r2 - dy * 5;
        wL1[tid] = w1[((oc * 4 + ic) * 5 + dy) * 5 + dx];
    }
#pragma unroll
    for (int s = 0; s < 2; ++s) {
        int hp = tid + s * 256;
        if (hp < HS1 * HS1) {
            int hy = hp / HS1, hx = hp - hy * HS1;
            int gy = Y0 + hy - 2, gx = X0 + hx - 2;
            uint4 lo = make_uint4(0, 0, 0, 0), hi = make_uint4(0, 0, 0, 0);
            if (gy >= 0 && gy < 128 && gx >= 0 && gx < 128) {
                const uint4* g = (const uint4*)
                    &xmg[((size_t)((n << 14) + gy * 128 + gx)) * 4];
                lo = g[0]; hi = g[1];
            }
            int li = hy * HP1 + hx;
            xs[0][li] = make_uint2(lo.x, lo.y);
            xs[1][li] = make_uint2(lo.z, lo.w);
            xs[2][li] = make_uint2(hi.x, hi.y);
            xs[3][li] = make_uint2(hi.z, hi.w);
        }
    }
    __syncthreads();

    const int cy = tid >> 4, cx = tid & 15;
    const int base = cy * HP1 + cx;

    float s1a[4] = {}, s2a[4] = {}, s1b[4] = {}, s2b[4] = {};
    unsigned long long om[4] = {};
    const float R1  = 0.36787944117144233f;   // exp(-1/1)
    const float CO1 = 2.7182818284590452f;    // e/1
    const float CRF = -54.365636569180902f;   // -20e

    for (int chk = 0; chk < 5; ++chk) {
        const int t0 = chk * TC;
        float a[TC][4];
#pragma unroll
        for (int u = 0; u < TC; ++u) { a[u][0]=0.f; a[u][1]=0.f; a[u][2]=0.f; a[u][3]=0.f; }
#pragma unroll 1
        for (int ic = 0; ic < 4; ++ic) {
            const uint2*  xp = &xs[ic][base];
            const float4* wp = (const float4*)&wL1[ic * 100];
#pragma unroll 1
            for (int dy = 0; dy < 5; ++dy) {
#pragma unroll
                for (int dx = 0; dx < 5; ++dx) {
                    uint2 m = xp[dx];
                    unsigned long long mm = ((unsigned long long)m.y << 32) | m.x;
                    unsigned win = (unsigned)(mm >> t0);
                    float4 w = wp[dx];
#pragma unroll
                    for (int u = 0; u < TC; ++u) {
                        float f = (float)((win >> u) & 1u);
                        a[u][0] = fmaf(f, w.x, a[u][0]);
                        a[u][1] = fmaf(f, w.y, a[u][1]);
                        a[u][2] = fmaf(f, w.z, a[u][2]);
                        a[u][3] = fmaf(f, w.w, a[u][3]);
                    }
                }
                xp += HP1; wp += 5;
            }
        }
        unsigned cm[4] = {0, 0, 0, 0};
#pragma unroll
        for (int u = 0; u < TC; ++u) {
#pragma unroll
            for (int oc = 0; oc < 4; ++oc) {
                float ao  = CO1 * s2a[oc];
                float ns1 = fmaf(R1, s1a[oc], a[u][oc]);
                s1a[oc] = ns1;
                s2a[oc] = fmaf(R1, s2a[oc], R1 * ns1);
                float mv = fmaf(CRF, s2b[oc], ao);
                unsigned b = (mv >= 20.f) ? 1u : 0u;
                float spf = (float)b;
                float nb1 = fmaf(R1, s1b[oc], spf);
                s1b[oc] = nb1;
                s2b[oc] = fmaf(R1, s2b[oc], R1 * nb1);
                cm[oc] |= b << u;
            }
        }
#pragma unroll
        for (int oc = 0; oc < 4; ++oc)
            om[oc] |= (unsigned long long)cm[oc] << t0;
    }

    uint4* g = (uint4*)&s1g[((size_t)((n << 14) + (Y0 + cy) * 128 + X0 + cx)) * 4];
    g[0] = make_uint4((unsigned)om[0], (unsigned)(om[0] >> 32),
                      (unsigned)om[1], (unsigned)(om[1] >> 32));
    g[1] = make_uint4((unsigned)om[2], (unsigned)(om[2] >> 32),
                      (unsigned)om[3], (unsigned)(om[3] >> 32));
}

// ---------------- kernel C: layer 2 + output expansion ----------------
#define HS2 18
#define HP2 19
__global__ __launch_bounds__(256)
void snn_l2(const uint2* __restrict__ s1g, const float* __restrict__ w2,
            float* __restrict__ out)
{
    __shared__ __align__(16) uint2 ss[4][HS2 * HP2];
    __shared__ __align__(16) float wL2[144];        // [ic][dy][dx][oc]
    __shared__ unsigned long long oml[256 * 4];

    const int tid = threadIdx.x;
    const int n = blockIdx.z, Y0 = blockIdx.y * 16, X0 = blockIdx.x * 16;

    if (tid < 144) {
        int oc = tid & 3, r = tid >> 2;
        int ic = r / 9, r2 = r - ic * 9;
        int dy = r2 / 3, dx = r2 - dy * 3;
        wL2[tid] = w2[((oc * 4 + ic) * 3 + dy) * 3 + dx];
    }
#pragma unroll
    for (int s = 0; s < 2; ++s) {
        int hp = tid + s * 256;
        if (hp < HS2 * HS2) {
            int hy = hp / HS2, hx = hp - hy * HS2;
            int gy = Y0 + hy - 1, gx = X0 + hx - 1;
            uint4 lo = make_uint4(0, 0, 0, 0), hi = make_uint4(0, 0, 0, 0);
            if (gy >= 0 && gy < 128 && gx >= 0 && gx < 128) {
                const uint4* g = (const uint4*)
                    &s1g[((size_t)((n << 14) + gy * 128 + gx)) * 4];
                lo = g[0]; hi = g[1];
            }
            int li = hy * HP2 + hx;
            ss[0][li] = make_uint2(lo.x, lo.y);
            ss[1][li] = make_uint2(lo.z, lo.w);
            ss[2][li] = make_uint2(hi.x, hi.y);
            ss[3][li] = make_uint2(hi.z, hi.w);
        }
    }
    __syncthreads();

    const int cy = tid >> 4, cx = tid & 15;
    const int base = cy * HP2 + cx;

    float s1c[4] = {}, s2c[4] = {}, s1d[4] = {}, s2d[4] = {};
    unsigned long long om[4] = {};
    const float R2  = 0.60653065971263342f;   // exp(-1/2)
    const float CO2 = 1.3591409142295226f;    // e/2
    const float CRF = -54.365636569180902f;   // -40e/2

    for (int chk = 0; chk < 5; ++chk) {
        const int t0 = chk * TC;
        float a[TC][4];
#pragma unroll
        for (int u = 0; u < TC; ++u) { a[u][0]=0.f; a[u][1]=0.f; a[u][2]=0.f; a[u][3]=0.f; }
#pragma unroll 1
        for (int ic = 0; ic < 4; ++ic) {
            const uint2*  sp = &ss[ic][base];
            const float4* wp = (const float4*)&wL2[ic * 36];
#pragma unroll 1
            for (int dy = 0; dy < 3; ++dy) {
#pragma unroll
                for (int dx = 0; dx < 3; ++dx) {
                    uint2 m = sp[dx];
                    unsigned long long mm = ((unsigned long long)m.y << 32) | m.x;
                    unsigned win = (unsigned)(mm >> t0);
                    float4 w = wp[dx];
#pragma unroll
                    for (int u = 0; u < TC; ++u) {
                        float f = (float)((win >> u) & 1u);
                        a[u][0] = fmaf(f, w.x, a[u][0]);
                        a[u][1] = fmaf(f, w.y, a[u][1]);
                        a[u][2] = fmaf(f, w.z, a[u][2]);
                        a[u][3] = fmaf(f, w.w, a[u][3]);
                    }
                }
                sp += HP2; wp += 3;
            }
        }
        unsigned cm[4] = {0, 0, 0, 0};
#pragma unroll
        for (int u = 0; u < TC; ++u) {
#pragma unroll
            for (int oc = 0; oc < 4; ++oc) {
                float ao  = CO2 * s2c[oc];
                float ns1 = fmaf(R2, s1c[oc], a[u][oc]);
                s1c[oc] = ns1;
                s2c[oc] = fmaf(R2, s2c[oc], R2 * ns1);
                float mv = fmaf(CRF, s2d[oc], ao);
                unsigned b = (mv >= 40.f) ? 1u : 0u;
                float spf = (float)b;
                float nd1 = fmaf(R2, s1d[oc], spf);
                s1d[oc] = nd1;
                s2d[oc] = fmaf(R2, s2d[oc], R2 * nd1);
                cm[oc] |= b << u;
            }
        }
#pragma unroll
        for (int oc = 0; oc < 4; ++oc)
            om[oc] |= (unsigned long long)cm[oc] << t0;
    }

    // coalesced output expansion via LDS transpose
#pragma unroll
    for (int oc = 0; oc < 4; ++oc) oml[tid * 4 + oc] = om[oc];
    __syncthreads();

    for (int i = tid; i < 256 * 4 * 25; i += 256) {
        int pc = i / 25;                // (pixel, channel)
        int j  = i - pc * 25;
        int p  = pc >> 2, c = pc & 3;
        unsigned long long m = oml[p * 4 + c];
        int py = p >> 4, px = p & 15;
        int k = 2 * j;
        float2 v;
        v.x = (float)((unsigned)(m >> k) & 1u);
        v.y = (float)((unsigned)(m >> (k + 1)) & 1u);
        float* o = out + ((size_t)(((n * 4 + c) << 14) + (Y0 + py) * 128 + X0 + px)) * 50;
        *(float2*)(o + k) = v;
    }
}

// ---------------- fallback: R6 single fused kernel (ws too small) ----------------
#define TW   16
#define TH   8
#define R1S  (TW + 6)
#define R1R  (TH + 6)
#define R1N  (R1S * R1R)
#define R2S  (TW + 2)
#define R2R  (TH + 2)
#define R2N  (R2S * R2R)

__global__ __launch_bounds__(256)
void snn_fused_fb(const float* __restrict__ xin,
                  const float* __restrict__ w1,
                  const float* __restrict__ w2,
                  float* __restrict__ out)
{
    __shared__ __align__(16) uint2    xm[4][R1N];
    __shared__ unsigned               s1m[4][R2N];
    __shared__ __align__(16) float    wL1[400];
    __shared__ __align__(16) float    wL2[144];

    const int tid = threadIdx.x;
    const int n   = blockIdx.z;
    const int Y0  = blockIdx.y * TH;
    const int X0  = blockIdx.x * TW;

    for (int i = tid; i < 400; i += 256) {
        int oc = i & 3, r = i >> 2;
        int ic = r / 25, r2 = r - ic * 25;
        int dy = r2 / 5, dx = r2 - dy * 5;
        wL1[i] = w1[((oc * 4 + ic) * 5 + dy) * 5 + dx];
    }
    if (tid < 144) {
        int oc = tid & 3, r = tid >> 2;
        int ic = r / 9, r2 = r - ic * 9;
        int dy = r2 / 3, dx = r2 - dy * 3;
        wL2[tid] = w2[((oc * 4 + ic) * 3 + dy) * 3 + dx];
    }
#pragma unroll
    for (int s = 0; s < 2; ++s) {
        int hp = tid + s * 256;
        if (hp < R1N) {
            int hy = hp / R1S, hx = hp - hy * R1S;
            int gy = Y0 + hy - 3, gx = X0 + hx - 3;
            bool inimg = gy >= 0 && gy < 128 && gx >= 0 && gx < 128;
#pragma unroll
            for (int c = 0; c < 4; ++c) {
                unsigned m0 = 0, m1 = 0;
                if (inimg) {
                    const float2* p = (const float2*)
                        (xin + ((size_t)(((n * 4 + c) * 128 + gy) * 128 + gx)) * 50);
#pragma unroll
                    for (int j = 0; j < 25; ++j) {
                        float2 v = p[j];
                        unsigned b0 = (v.x != 0.f) ? 1u : 0u;
                        unsigned b1 = (v.y != 0.f) ? 1u : 0u;
                        int k = 2 * j;
                        if (k < 32) m0 |= (b0 << k) | (b1 << (k + 1));
                        else        m1 |= (b0 << (k - 32)) | (b1 << (k - 31));
                    }
                }
                xm[c][hp] = make_uint2(m0, m1);
            }
        }
    }
    const bool cw = (tid < R2N);
    const int cy = tid / R2S;
    const int cx = tid - cy * R2S;
    const bool cin = cw && (Y0 + cy - 1) >= 0 && (Y0 + cy - 1) < 128
                        && (X0 + cx - 1) >= 0 && (X0 + cx - 1) < 128;
    const int xbase = cy * R1S + cx;
    const bool iw = (tid < TW * TH);
    const int iy = tid >> 4, ix = tid & 15;
    const int ibase = iy * R2S + ix;

    float s1a[4] = {}, s2a[4] = {}, s1b[4] = {}, s2b[4] = {};
    float s1c[4] = {}, s2c[4] = {}, s1d[4] = {}, s2d[4] = {};
    unsigned long long om[4] = {};

    const float R1  = 0.36787944117144233f;
    const float CO1 = 2.7182818284590452f;
    const float R2  = 0.60653065971263342f;
    const float CO2 = 1.3591409142295226f;
    const float CRF = -54.365636569180902f;

    __syncthreads();

    for (int chk = 0; chk < 5; ++chk) {
        const int t0 = chk * TC;
        if (cw) {
            float a[TC][4];
#pragma unroll
            for (int u = 0; u < TC; ++u) { a[u][0]=0.f; a[u][1]=0.f; a[u][2]=0.f; a[u][3]=0.f; }
            if (cin) {
#pragma unroll 1
                for (int ic = 0; ic < 4; ++ic) {
                    const uint2*  xp = &xm[ic][xbase];
                    const float4* wp = (const float4*)&wL1[ic * 100];
#pragma unroll 1
                    for (int dy = 0; dy < 5; ++dy) {
#pragma unroll
                        for (int dx = 0; dx < 5; ++dx) {
                            uint2 m = xp[dx];
                            unsigned long long mm =
                                ((unsigned long long)m.y << 32) | m.x;
                            unsigned win = (unsigned)(mm >> t0);
                            float4 w = wp[dx];
#pragma unroll
                            for (int u = 0; u < TC; ++u) {
                                float f = (float)((win >> u) & 1u);
                                a[u][0] = fmaf(f, w.x, a[u][0]);
                                a[u][1] = fmaf(f, w.y, a[u][1]);
                                a[u][2] = fmaf(f, w.z, a[u][2]);
                                a[u][3] = fmaf(f, w.w, a[u][3]);
                            }
                        }
                        xp += R1S; wp += 5;
                    }
                }
            }
            unsigned cm[4] = {0, 0, 0, 0};
#pragma unroll
            for (int u = 0; u < TC; ++u) {
#pragma unroll
                for (int oc = 0; oc < 4; ++oc) {
                    float ao  = CO1 * s2a[oc];
                    float ns1 = fmaf(R1, s1a[oc], a[u][oc]);
                    s1a[oc] = ns1;
                    s2a[oc] = fmaf(R1, s2a[oc], R1 * ns1);
                    float mv = fmaf(CRF, s2b[oc], ao);
                    unsigned b = (mv >= 20.f) ? 1u : 0u;
                    float spf = (float)b;
                    float nb1 = fmaf(R1, s1b[oc], spf);
                    s1b[oc] = nb1;
                    s2b[oc] = fmaf(R1, s2b[oc], R1 * nb1);
                    cm[oc] |= b << u;
                }
            }
            s1m[0][tid] = cm[0];
            s1m[1][tid] = cm[1];
            s1m[2][tid] = cm[2];
            s1m[3][tid] = cm[3];
        }
        __syncthreads();
        if (iw) {
            float a[TC][4];
#pragma unroll
            for (int u = 0; u < TC; ++u) { a[u][0]=0.f; a[u][1]=0.f; a[u][2]=0.f; a[u][3]=0.f; }
#pragma unroll 1
            for (int ic = 0; ic < 4; ++ic) {
                const unsigned* sp = &s1m[ic][ibase];
                const float4*   wp = (const float4*)&wL2[ic * 36];
#pragma unroll 1
                for (int dy = 0; dy < 3; ++dy) {
#pragma unroll
                    for (int dx = 0; dx < 3; ++dx) {
                        unsigned win = sp[dx];
                        float4 w = wp[dx];
#pragma unroll
                        for (int u = 0; u < TC; ++u) {
                            float f = (float)((win >> u) & 1u);
                            a[u][0] = fmaf(f, w.x, a[u][0]);
                            a[u][1] = fmaf(f, w.y, a[u][1]);
                            a[u][2] = fmaf(f, w.z, a[u][2]);
                            a[u][3] = fmaf(f, w.w, a[u][3]);
                        }
                    }
                    sp += R2S; wp += 3;
                }
            }
            unsigned cm[4] = {0, 0, 0, 0};
#pragma unroll
            for (int u = 0; u < TC; ++u) {
#pragma unroll
                for (int oc = 0; oc < 4; ++oc) {
                    float ao  = CO2 * s2c[oc];
                    float ns1 = fmaf(R2, s1c[oc], a[u][oc]);
                    s1c[oc] = ns1;
                    s2c[oc] = fmaf(R2, s2c[oc], R2 * ns1);
                    float mv = fmaf(CRF, s2d[oc], ao);
                    unsigned b = (mv >= 40.f) ? 1u : 0u;
                    float spf = (float)b;
                    float nd1 = fmaf(R2, s1d[oc], spf);
                    s1d[oc] = nd1;
                    s2d[oc] = fmaf(R2, s2d[oc], R2 * nd1);
                    cm[oc] |= b << u;
                }
            }
#pragma unroll
            for (int oc = 0; oc < 4; ++oc)
                om[oc] |= (unsigned long long)cm[oc] << t0;
        }
        __syncthreads();
    }
    if (iw) {
#pragma unroll
        for (int c = 0; c < 4; ++c) {
            float* p = out + ((size_t)(((n * 4 + c) * 128 + (Y0 + iy)) * 128 + (X0 + ix))) * 50;
            unsigned long long m = om[c];
#pragma unroll
            for (int j = 0; j < 25; ++j) {
                int k = 2 * j;
                float2 v;
                v.x = (float)((unsigned)(m >> k) & 1u);
                v.y = (float)((unsigned)(m >> (k + 1)) & 1u);
                *(float2*)(p + k) = v;
            }
        }
    }
}

extern "C" void kernel_launch(void* const* d_in, const int* in_sizes, int n_in,
                              void* d_out, int out_size, void* d_ws, size_t ws_size,
                              hipStream_t stream) {
    (void)in_sizes; (void)n_in; (void)out_size;
    const float* x  = (const float*)d_in[0];
    const float* w1 = (const float*)d_in[1];
    const float* w2 = (const float*)d_in[2];
    float* o = (float*)d_out;

    if (ws_size >= 2u * 4194304u) {
        uint2* xmg = (uint2*)d_ws;            // 524288 uint2 = 4 MB
        uint2* s1g = xmg + 524288;            // 4 MB
        hipLaunchKernelGGL(snn_pack, dim3(2048), dim3(256), 0, stream, x, xmg);
        hipLaunchKernelGGL(snn_l1, dim3(8, 8, 8), dim3(256), 0, stream, xmg, w1, s1g);
        hipLaunchKernelGGL(snn_l2, dim3(8, 8, 8), dim3(256), 0, stream, s1g, w2, o);
    } else {
        dim3 grid(128 / TW, 128 / TH, 8);
        hipLaunchKernelGGL(snn_fused_fb, grid, dim3(256), 0, stream, x, w1, w2, o);
    }
}